// Round 7
// baseline (52.454 us; speedup 1.0000x reference)
//
#include <hip/hip_runtime.h>
#include <math.h>

// zc layout: [(j2*16 + kko)][3072 rows][32 w] bf16, chunk-swizzled: logical 8-elem
//   chunk g of row r stored at chunk (g ^ ((r>>1)&3)). Plane = 98304 elems.
// dw layout: [kko(16)][512 k][32 w] bf16, same swizzle keyed on k.
#define ZSLAB 98304
#define DSLAB 16384

typedef __attribute__((ext_vector_type(8))) __bf16 bf16x8;
typedef __attribute__((ext_vector_type(4))) float  f32x4;

__device__ __forceinline__ unsigned short f2bf(float f) {
  union { float f; unsigned u; } v; v.f = f;
  unsigned r = v.u + 0x7fffu + ((v.u >> 16) & 1u);   // RNE
  return (unsigned short)(r >> 16);
}
__device__ __forceinline__ float bf2f(unsigned short s) {
  union { unsigned u; float f; } v; v.u = ((unsigned)s) << 16;
  return v.f;
}

__device__ const float DBC[8][8] = {
  { 0.35355339f,  0.35355339f,  0.35355339f,  0.35355339f,  0.35355339f,  0.35355339f,  0.35355339f,  0.35355339f},
  { 0.49039264f,  0.41573481f,  0.27778512f,  0.09754516f, -0.09754516f, -0.27778512f, -0.41573481f, -0.49039264f},
  { 0.46193977f,  0.19134172f, -0.19134172f, -0.46193977f, -0.46193977f, -0.19134172f,  0.19134172f,  0.46193977f},
  { 0.41573481f, -0.09754516f, -0.49039264f, -0.27778512f,  0.27778512f,  0.49039264f,  0.09754516f, -0.41573481f},
  { 0.35355339f, -0.35355339f, -0.35355339f,  0.35355339f,  0.35355339f, -0.35355339f, -0.35355339f,  0.35355339f},
  { 0.27778512f, -0.49039264f,  0.09754516f,  0.41573481f, -0.41573481f, -0.09754516f,  0.49039264f, -0.27778512f},
  { 0.19134172f, -0.46193977f,  0.46193977f, -0.19134172f, -0.19134172f,  0.46193977f, -0.46193977f,  0.19134172f},
  { 0.09754516f, -0.27778512f,  0.41573481f, -0.49039264f,  0.49039264f, -0.41573481f,  0.27778512f, -0.09754516f}
};

// ---------------- 1) pack + dw build fused. grid (512, 2) x 256 threads.
__global__ __launch_bounds__(256) void pack_all(const float* __restrict__ x,
                                                unsigned short* __restrict__ zc,
                                                unsigned short* __restrict__ dwf) {
  const int h = blockIdx.x, t = threadIdx.x;

  // --- one Dw element per thread (262144 threads == 512*512 elements)
  {
    const int idx = (blockIdx.y * 512 + blockIdx.x) * 256 + t;
    const int k = idx >> 9, w = idx & 511;
    const int n = (k * (2 * w + 1)) & 2047;                     // exact angle reduction
    const float c = __cosf((float)n * 0.0030679615757712823f);  // pi/1024
    const float scale = (k == 0) ? 0.04419417382415922f : 0.0625f;
    const int kko = w >> 5, g = (w >> 3) & 3, e = w & 7, s = (k >> 1) & 3;
    dwf[(size_t)kko * DSLAB + k * 32 + ((g ^ s) << 3) + e] = f2bf(c * scale);
  }

  // --- pack: q = floor(255x), Db rows m=2..7, emit swizzled planes
  const int c0 = blockIdx.y * 2048 + t * 8;   // this thread's 8 cols = one w, all j
  const float* xb = x + (size_t)(h * 8) * 4096 + c0;
  float q[8][8];
#pragma unroll
  for (int i = 0; i < 8; ++i) {
    float4 a = *reinterpret_cast<const float4*>(xb + (size_t)i * 4096);
    float4 b = *reinterpret_cast<const float4*>(xb + (size_t)i * 4096 + 4);
    q[i][0] = floorf(a.x * 255.0f); q[i][1] = floorf(a.y * 255.0f);
    q[i][2] = floorf(a.z * 255.0f); q[i][3] = floorf(a.w * 255.0f);
    q[i][4] = floorf(b.x * 255.0f); q[i][5] = floorf(b.y * 255.0f);
    q[i][6] = floorf(b.z * 255.0f); q[i][7] = floorf(b.w * 255.0f);
  }
  const int w0 = c0 >> 3;
  const int kko = w0 >> 5, g = (w0 >> 3) & 3, e = w0 & 7;
#pragma unroll
  for (int m = 2; m < 8; ++m) {
    const int row = h * 6 + (m - 2);
    const int s = (row >> 1) & 3;
    const size_t base = (size_t)row * 32 + ((g ^ s) << 3) + e;
#pragma unroll
    for (int j = 2; j < 8; ++j) {
      float v = 0.0f;
#pragma unroll
      for (int i = 0; i < 8; ++i) v = fmaf(DBC[m][i], q[i][j], v);
      zc[(size_t)((j - 2) * 16 + kko) * ZSLAB + base] = f2bf(v);
    }
  }
}

// ---------------- 2) fused batched-GEMM + interleave — barrier-free per-wave pipelines
// Block (mt 0..63, nt 0..15): out rows [mt*64,+64), cols [nt*256,+256).
// 6 waves; wave wv owns j = wv+2: M=48 (3 frags), N=32 (2 frags), K=512, BK=32.
// B (32 KB, whole K) preloaded once; A staged per-wave (2x3KB dbuf, vmcnt(3) counted).
__device__ __forceinline__ void gload16(const unsigned short* g, unsigned short* l) {
  __builtin_amdgcn_global_load_lds(
      (__attribute__((address_space(1))) void*)(g),
      (__attribute__((address_space(3))) void*)(l),
      16, 0, 0);
}

__global__ __launch_bounds__(384, 3) void fused_dct(const unsigned short* __restrict__ zc,
                                                    const unsigned short* __restrict__ dwf,
                                                    float* __restrict__ out) {
  const int bid = blockIdx.x;     // bid = nt*64+mt -> XCD = mt%8: same-mt blocks share L2
  const int mt  = bid & 63;
  const int nt  = bid >> 6;

  // LDS map (69632 B -> 2 blocks/CU):
  //   [Bsh: 0..32767]  (resident all K)   [Awave: 32768 + wv*6144 + buf*3072]
  //   Obuf (19584 B) aliases Bsh, gated by __syncthreads after the K-loop.
  __shared__ __align__(16) unsigned char SM[69632];
  unsigned short* Bsh  = (unsigned short*)SM;
  unsigned short* Obuf = (unsigned short*)SM;

  const int tid  = threadIdx.x;
  const int lane = tid & 63;
  const int wv   = tid >> 6;        // 0..5 = j-2
  const int l15  = lane & 15;

  const unsigned short* Asrc = zc + (size_t)(wv * 16) * ZSLAB + (size_t)mt * 1536;
  unsigned short* Abuf = (unsigned short*)(SM + 32768 + wv * 6144);

  f32x4 acc[3][2] = {};

  // ---- B preload: 16 chunks of 1024 elems (2KB); wave wv takes chunks wv, wv+6, wv+12.
  for (int c = wv; c < 16; c += 6) {
#pragma unroll
    for (int hf = 0; hf < 2; ++hf)
      gload16(dwf + (size_t)c * DSLAB + nt * 1024 + hf * 512 + lane * 8,
              Bsh + c * 1024 + hf * 512 + lane * 8);
  }
  __syncthreads();                 // drains vmcnt(0); B visible to all waves

  // ---- per-wave async A pipeline, 2-deep, zero barriers
#define STAGE_A(buf, kko)                                                            \
  do {                                                                               \
    _Pragma("unroll")                                                                \
    for (int q_ = 0; q_ < 3; ++q_)                                                   \
      gload16(Asrc + (size_t)(kko) * ZSLAB + q_ * 512 + lane * 8,                    \
              Abuf + (buf) * 1536 + q_ * 512 + lane * 8);                            \
  } while (0)

  STAGE_A(0, 0);
  STAGE_A(1, 1);
#pragma unroll
  for (int t = 0; t < 16; ++t) {
    if (t < 15) { asm volatile("s_waitcnt vmcnt(3)" ::: "memory"); }
    else        { asm volatile("s_waitcnt vmcnt(0)" ::: "memory"); }
    const unsigned short* Ap = Abuf + (t & 1) * 1536;
    const unsigned short* Bp = Bsh + t * 1024;
    bf16x8 bfr[2];
#pragma unroll
    for (int nf = 0; nf < 2; ++nf) {
      const int r_ = nf * 16 + l15;
      bfr[nf] = *reinterpret_cast<const bf16x8*>(
          Bp + r_ * 32 + (((lane >> 4) ^ ((r_ >> 1) & 3)) << 3));
    }
#pragma unroll
    for (int mf = 0; mf < 3; ++mf) {
      const int r_ = mf * 16 + l15;
      const bf16x8 afr = *reinterpret_cast<const bf16x8*>(
          Ap + r_ * 32 + (((lane >> 4) ^ ((r_ >> 1) & 3)) << 3));
      acc[mf][0] = __builtin_amdgcn_mfma_f32_16x16x32_bf16(afr, bfr[0], acc[mf][0], 0, 0, 0);
      acc[mf][1] = __builtin_amdgcn_mfma_f32_16x16x32_bf16(afr, bfr[1], acc[mf][1], 0, 0, 0);
    }
    if (t < 14) {
      asm volatile("s_waitcnt lgkmcnt(0)" ::: "memory");  // own ds_reads of buf[t&1] done
      STAGE_A(t & 1, t + 2);                              // overwrite with stage t+2
    }
  }
#undef STAGE_A

  __syncthreads();                 // all waves done reading Bsh -> Obuf may alias it

  // ---- C -> Obuf (plane wv = j-2), 48 rows, pitch 34
  unsigned short* Ob = Obuf + wv * 1632;
#pragma unroll
  for (int mf = 0; mf < 3; ++mf)
#pragma unroll
    for (int nf = 0; nf < 2; ++nf)
#pragma unroll
      for (int p = 0; p < 4; ++p)
        Ob[(mf * 16 + (lane >> 4) * 4 + p) * 34 + nf * 16 + l15] = f2bf(acc[mf][nf][p]);
  __syncthreads();

  // ---- epilogue: 64 rows x 256 f32 cols, coalesced f32x4 incl. mask zeros
  float* outb = out + (size_t)(mt * 64) * 4096 + nt * 256;
  for (int v = tid; v < 4096; v += 384) {
    const int row64 = v >> 6;
    const int c4 = (v & 63) << 2;
    f32x4 val = {0.0f, 0.0f, 0.0f, 0.0f};
    const int m = row64 & 7;
    if (m >= 2) {
      const int row48 = (row64 >> 3) * 6 + (m - 2);
      const int kk = c4 >> 3, jb = c4 & 4;
#pragma unroll
      for (int e = 0; e < 4; ++e) {
        const int j = jb + e;
        if (j >= 2)
          val[e] = bf2f(Obuf[(j - 2) * 1632 + row48 * 34 + kk]);
      }
    }
    *reinterpret_cast<f32x4*>(outb + (size_t)row64 * 4096 + c4) = val;
  }
}

extern "C" void kernel_launch(void* const* d_in, const int* in_sizes, int n_in,
                              void* d_out, int out_size, void* d_ws, size_t ws_size,
                              hipStream_t stream) {
  const float* x = (const float*)d_in[0];
  float* out = (float*)d_out;
  char* ws = (char*)d_ws;

  unsigned short* dwf = (unsigned short*)ws;             // 512 KB
  unsigned short* zc  = (unsigned short*)(ws + 524288);  // 18.87 MB

  pack_all<<<dim3(512, 2), 256, 0, stream>>>(x, zc, dwf);
  fused_dct<<<1024, 384, 0, stream>>>(zc, dwf, out);
}

// Round 8
// 49.661 us; speedup vs baseline: 1.0562x; 1.0562x over previous
//
#include <hip/hip_runtime.h>
#include <math.h>

// zc layout (UNSWIZZLED now): [(j2*16 + kko)][3072 rows][32 w] bf16; plane = 98304 elems.
//   A-fragment of lane (l15,hi) for frag mf, stage t: 16 contiguous bytes at
//   (wv*16+t)*ZSLAB + (mt*48 + mf*16 + l15)*32 + hi*8  -> direct global->VGPR loads.
// dw layout: [kko(16)][512 k][32 w] bf16, chunk-swizzled on k: chunk g stored at g^((k>>1)&3).
#define ZSLAB 98304
#define DSLAB 16384

typedef __attribute__((ext_vector_type(8))) __bf16 bf16x8;
typedef __attribute__((ext_vector_type(4))) float  f32x4;

__device__ __forceinline__ unsigned short f2bf(float f) {
  union { float f; unsigned u; } v; v.f = f;
  unsigned r = v.u + 0x7fffu + ((v.u >> 16) & 1u);   // RNE
  return (unsigned short)(r >> 16);
}
__device__ __forceinline__ float bf2f(unsigned short s) {
  union { unsigned u; float f; } v; v.u = ((unsigned)s) << 16;
  return v.f;
}

__device__ const float DBC[8][8] = {
  { 0.35355339f,  0.35355339f,  0.35355339f,  0.35355339f,  0.35355339f,  0.35355339f,  0.35355339f,  0.35355339f},
  { 0.49039264f,  0.41573481f,  0.27778512f,  0.09754516f, -0.09754516f, -0.27778512f, -0.41573481f, -0.49039264f},
  { 0.46193977f,  0.19134172f, -0.19134172f, -0.46193977f, -0.46193977f, -0.19134172f,  0.19134172f,  0.46193977f},
  { 0.41573481f, -0.09754516f, -0.49039264f, -0.27778512f,  0.27778512f,  0.49039264f,  0.09754516f, -0.41573481f},
  { 0.35355339f, -0.35355339f, -0.35355339f,  0.35355339f,  0.35355339f, -0.35355339f, -0.35355339f,  0.35355339f},
  { 0.27778512f, -0.49039264f,  0.09754516f,  0.41573481f, -0.41573481f, -0.09754516f,  0.49039264f, -0.27778512f},
  { 0.19134172f, -0.46193977f,  0.46193977f, -0.19134172f, -0.19134172f,  0.46193977f, -0.46193977f,  0.19134172f},
  { 0.09754516f, -0.27778512f,  0.41573481f, -0.49039264f,  0.49039264f, -0.41573481f,  0.27778512f, -0.09754516f}
};

// ---------------- 1) pack + dw build fused. grid (512, 2) x 256 threads.
__global__ __launch_bounds__(256) void pack_all(const float* __restrict__ x,
                                                unsigned short* __restrict__ zc,
                                                unsigned short* __restrict__ dwf) {
  const int h = blockIdx.x, t = threadIdx.x;

  // --- one Dw element per thread (262144 threads == 512*512 elements), swizzled
  {
    const int idx = (blockIdx.y * 512 + blockIdx.x) * 256 + t;
    const int k = idx >> 9, w = idx & 511;
    const int n = (k * (2 * w + 1)) & 2047;                     // exact angle reduction
    const float c = __cosf((float)n * 0.0030679615757712823f);  // pi/1024
    const float scale = (k == 0) ? 0.04419417382415922f : 0.0625f;
    const int kko = w >> 5, g = (w >> 3) & 3, e = w & 7, s = (k >> 1) & 3;
    dwf[(size_t)kko * DSLAB + k * 32 + ((g ^ s) << 3) + e] = f2bf(c * scale);
  }

  // --- pack: q = floor(255x), Db rows m=2..7, emit UNSWIZZLED planes
  const int c0 = blockIdx.y * 2048 + t * 8;   // this thread's 8 cols = one w, all j
  const float* xb = x + (size_t)(h * 8) * 4096 + c0;
  float q[8][8];
#pragma unroll
  for (int i = 0; i < 8; ++i) {
    float4 a = *reinterpret_cast<const float4*>(xb + (size_t)i * 4096);
    float4 b = *reinterpret_cast<const float4*>(xb + (size_t)i * 4096 + 4);
    q[i][0] = floorf(a.x * 255.0f); q[i][1] = floorf(a.y * 255.0f);
    q[i][2] = floorf(a.z * 255.0f); q[i][3] = floorf(a.w * 255.0f);
    q[i][4] = floorf(b.x * 255.0f); q[i][5] = floorf(b.y * 255.0f);
    q[i][6] = floorf(b.z * 255.0f); q[i][7] = floorf(b.w * 255.0f);
  }
  const int w0 = c0 >> 3;
  const int kko = w0 >> 5, w31 = w0 & 31;
#pragma unroll
  for (int m = 2; m < 8; ++m) {
    const int row = h * 6 + (m - 2);
    const size_t base = (size_t)row * 32 + w31;
#pragma unroll
    for (int j = 2; j < 8; ++j) {
      float v = 0.0f;
#pragma unroll
      for (int i = 0; i < 8; ++i) v = fmaf(DBC[m][i], q[i][j], v);
      zc[(size_t)((j - 2) * 16 + kko) * ZSLAB + base] = f2bf(v);
    }
  }
}

// ---------------- 2) fused GEMM + interleave: A global->VGPR (asm, counted vmcnt),
// B LDS-resident whole-K, zero K-loop barriers. Block (mt 0..63, nt 0..15).
// 6 waves; wave wv owns j = wv+2: M=48 (3 frags), N=32 (2 frags), K=512, BK=32.
__device__ __forceinline__ void gload16(const unsigned short* g, unsigned short* l) {
  __builtin_amdgcn_global_load_lds(
      (__attribute__((address_space(1))) void*)(g),
      (__attribute__((address_space(3))) void*)(l),
      16, 0, 0);
}

__global__ __launch_bounds__(384, 6) void fused_dct(const unsigned short* __restrict__ zc,
                                                    const unsigned short* __restrict__ dwf,
                                                    float* __restrict__ out) {
  const int bid = blockIdx.x;     // bid = nt*64+mt -> XCD = mt%8: same-mt blocks share L2
  const int mt  = bid & 63;
  const int nt  = bid >> 6;

  // LDS = 32 KB: Bsh (whole-K B) resident during K-loop; Obuf (19.6 KB) aliases it
  // afterwards, gated by __syncthreads.
  __shared__ __align__(16) unsigned char SM[32768];
  unsigned short* Bsh  = (unsigned short*)SM;
  unsigned short* Obuf = (unsigned short*)SM;

  const int tid  = threadIdx.x;
  const int lane = tid & 63;
  const int wv   = tid >> 6;        // 0..5 = j-2
  const int l15  = lane & 15;
  const int hi   = lane >> 4;

  // ---- B preload: 16 planes x 2KB; wave wv covers planes wv, wv+6, wv+12.
  for (int c = wv; c < 16; c += 6) {
#pragma unroll
    for (int hf = 0; hf < 2; ++hf)
      gload16(dwf + (size_t)c * DSLAB + nt * 1024 + hf * 512 + lane * 8,
              Bsh + c * 1024 + hf * 512 + lane * 8);
  }
  __syncthreads();                 // drains vmcnt(0): B visible; vmcnt == 0 entering loop

  f32x4 acc[3][2] = {};
  const unsigned short* pA0 = zc + (size_t)(wv * 16) * ZSLAB
                              + (size_t)(mt * 48 + l15) * 32 + hi * 8;   // stage 0
  const unsigned short* pA1 = pA0 + ZSLAB;                               // stage 1

  bf16x8 a0[3], a1[3];             // ping-pong A fragments (static-indexed, rule #20)

  // 3 frag loads per stage; frag mf at +mf*1024 B (16 rows x 64 B).
#define ISSUE(dst, p)                                                     \
  asm volatile("global_load_dwordx4 %0, %3, off\n\t"                     \
               "global_load_dwordx4 %1, %3, off offset:1024\n\t"         \
               "global_load_dwordx4 %2, %3, off offset:2048"             \
               : "=&v"(dst[0]), "=&v"(dst[1]), "=&v"(dst[2])             \
               : "v"(p)                                                   \
               : "memory")

  // rule #18: sched_barrier(0) right after a manual waitcnt, else MFMA hoists past it.
#define WAITV(n)                                                          \
  do {                                                                    \
    asm volatile("s_waitcnt vmcnt(" #n ")" ::: "memory");                 \
    __builtin_amdgcn_sched_barrier(0);                                    \
  } while (0)

#define COMPUTE(AS, t)                                                               \
  do {                                                                               \
    const unsigned short* Bp = Bsh + (t) * 1024;                                     \
    bf16x8 bfr[2];                                                                   \
    _Pragma("unroll")                                                                \
    for (int nf = 0; nf < 2; ++nf) {                                                 \
      const int r_ = nf * 16 + l15;                                                  \
      bfr[nf] = *reinterpret_cast<const bf16x8*>(                                    \
          Bp + r_ * 32 + ((hi ^ ((r_ >> 1) & 3)) << 3));                             \
    }                                                                                \
    _Pragma("unroll")                                                                \
    for (int mf = 0; mf < 3; ++mf) {                                                 \
      acc[mf][0] = __builtin_amdgcn_mfma_f32_16x16x32_bf16(AS[mf], bfr[0], acc[mf][0], 0, 0, 0); \
      acc[mf][1] = __builtin_amdgcn_mfma_f32_16x16x32_bf16(AS[mf], bfr[1], acc[mf][1], 0, 0, 0); \
    }                                                                                \
  } while (0)

  ISSUE(a0, pA0); pA0 += 2 * ZSLAB;
  ISSUE(a1, pA1); pA1 += 2 * ZSLAB;
#pragma unroll
  for (int tt = 0; tt < 16; tt += 2) {
    WAITV(3);                                  // stage tt landed; tt+1 still in flight
    COMPUTE(a0, tt);
    if (tt < 14) { ISSUE(a0, pA0); pA0 += 2 * ZSLAB; }   // stage tt+2 (WAR: after MFMAs)
    if (tt < 14) { WAITV(3); } else { WAITV(0); }        // stage tt+1 landed
    COMPUTE(a1, tt + 1);
    if (tt < 13) { ISSUE(a1, pA1); pA1 += 2 * ZSLAB; }   // stage tt+3
  }
#undef ISSUE
#undef WAITV
#undef COMPUTE

  __syncthreads();                 // all waves done reading Bsh -> Obuf may alias it

  // ---- C -> Obuf (plane wv = j-2), 48 rows, pitch 34
  unsigned short* Ob = Obuf + wv * 1632;
#pragma unroll
  for (int mf = 0; mf < 3; ++mf)
#pragma unroll
    for (int nf = 0; nf < 2; ++nf)
#pragma unroll
      for (int p = 0; p < 4; ++p)
        Ob[(mf * 16 + (lane >> 4) * 4 + p) * 34 + nf * 16 + l15] = f2bf(acc[mf][nf][p]);
  __syncthreads();

  // ---- epilogue: 64 rows x 256 f32 cols, coalesced f32x4 incl. mask zeros
  float* outb = out + (size_t)(mt * 64) * 4096 + nt * 256;
  for (int v = tid; v < 4096; v += 384) {
    const int row64 = v >> 6;
    const int c4 = (v & 63) << 2;
    f32x4 val = {0.0f, 0.0f, 0.0f, 0.0f};
    const int m = row64 & 7;
    if (m >= 2) {
      const int row48 = (row64 >> 3) * 6 + (m - 2);
      const int kk = c4 >> 3, jb = c4 & 4;
#pragma unroll
      for (int e = 0; e < 4; ++e) {
        const int j = jb + e;
        if (j >= 2)
          val[e] = bf2f(Obuf[(j - 2) * 1632 + row48 * 34 + kk]);
      }
    }
    *reinterpret_cast<f32x4*>(outb + (size_t)row64 * 4096 + c4) = val;
  }
}

extern "C" void kernel_launch(void* const* d_in, const int* in_sizes, int n_in,
                              void* d_out, int out_size, void* d_ws, size_t ws_size,
                              hipStream_t stream) {
  const float* x = (const float*)d_in[0];
  float* out = (float*)d_out;
  char* ws = (char*)d_ws;

  unsigned short* dwf = (unsigned short*)ws;             // 512 KB
  unsigned short* zc  = (unsigned short*)(ws + 524288);  // 18.87 MB

  pack_all<<<dim3(512, 2), 256, 0, stream>>>(x, zc, dwf);
  fused_dct<<<1024, 384, 0, stream>>>(zc, dwf, out);
}

// Round 10
// 43.346 us; speedup vs baseline: 1.2101x; 1.1457x over previous
//
#include <hip/hip_runtime.h>
#include <math.h>

// zc layout: [(j2*16 + kko)][3072 rows][32 w] bf16, chunk-swizzled: logical 8-elem
//   chunk g of row r stored at chunk (g ^ ((r>>1)&3)). Plane = 98304 elems.
// dw layout: [kko(16)][512 k][32 w] bf16, same swizzle keyed on k.
#define ZSLAB 98304
#define DSLAB 16384

typedef __attribute__((ext_vector_type(8))) __bf16 bf16x8;
typedef __attribute__((ext_vector_type(4))) float  f32x4;

__device__ __forceinline__ unsigned short f2bf(float f) {
  union { float f; unsigned u; } v; v.f = f;
  unsigned r = v.u + 0x7fffu + ((v.u >> 16) & 1u);   // RNE
  return (unsigned short)(r >> 16);
}
__device__ __forceinline__ float bf2f(unsigned short s) {
  union { unsigned u; float f; } v; v.u = ((unsigned)s) << 16;
  return v.f;
}

__device__ const float DBC[8][8] = {
  { 0.35355339f,  0.35355339f,  0.35355339f,  0.35355339f,  0.35355339f,  0.35355339f,  0.35355339f,  0.35355339f},
  { 0.49039264f,  0.41573481f,  0.27778512f,  0.09754516f, -0.09754516f, -0.27778512f, -0.41573481f, -0.49039264f},
  { 0.46193977f,  0.19134172f, -0.19134172f, -0.46193977f, -0.46193977f, -0.19134172f,  0.19134172f,  0.46193977f},
  { 0.41573481f, -0.09754516f, -0.49039264f, -0.27778512f,  0.27778512f,  0.49039264f,  0.09754516f, -0.41573481f},
  { 0.35355339f, -0.35355339f, -0.35355339f,  0.35355339f,  0.35355339f, -0.35355339f, -0.35355339f,  0.35355339f},
  { 0.27778512f, -0.49039264f,  0.09754516f,  0.41573481f, -0.41573481f, -0.09754516f,  0.49039264f, -0.27778512f},
  { 0.19134172f, -0.46193977f,  0.46193977f, -0.19134172f, -0.19134172f,  0.46193977f, -0.46193977f,  0.19134172f},
  { 0.09754516f, -0.27778512f,  0.41573481f, -0.49039264f,  0.49039264f, -0.41573481f,  0.27778512f, -0.09754516f}
};

// ---------------- 1) pack + dw build fused. grid (512, 2) x 256 threads.
__global__ __launch_bounds__(256) void pack_all(const float* __restrict__ x,
                                                unsigned short* __restrict__ zc,
                                                unsigned short* __restrict__ dwf) {
  const int h = blockIdx.x, t = threadIdx.x;

  // --- one Dw element per thread (262144 threads == 512*512 elements)
  {
    const int idx = (blockIdx.y * 512 + blockIdx.x) * 256 + t;
    const int k = idx >> 9, w = idx & 511;
    const int n = (k * (2 * w + 1)) & 2047;                     // exact angle reduction
    const float c = __cosf((float)n * 0.0030679615757712823f);  // pi/1024
    const float scale = (k == 0) ? 0.04419417382415922f : 0.0625f;
    const int kko = w >> 5, g = (w >> 3) & 3, e = w & 7, s = (k >> 1) & 3;
    dwf[(size_t)kko * DSLAB + k * 32 + ((g ^ s) << 3) + e] = f2bf(c * scale);
  }

  // --- pack: q = floor(255x), Db rows m=2..7, emit swizzled planes
  const int c0 = blockIdx.y * 2048 + t * 8;   // this thread's 8 cols = one w, all j
  const float* xb = x + (size_t)(h * 8) * 4096 + c0;
  float q[8][8];
#pragma unroll
  for (int i = 0; i < 8; ++i) {
    float4 a = *reinterpret_cast<const float4*>(xb + (size_t)i * 4096);
    float4 b = *reinterpret_cast<const float4*>(xb + (size_t)i * 4096 + 4);
    q[i][0] = floorf(a.x * 255.0f); q[i][1] = floorf(a.y * 255.0f);
    q[i][2] = floorf(a.z * 255.0f); q[i][3] = floorf(a.w * 255.0f);
    q[i][4] = floorf(b.x * 255.0f); q[i][5] = floorf(b.y * 255.0f);
    q[i][6] = floorf(b.z * 255.0f); q[i][7] = floorf(b.w * 255.0f);
  }
  const int w0 = c0 >> 3;
  const int kko = w0 >> 5, g = (w0 >> 3) & 3, e = w0 & 7;
#pragma unroll
  for (int m = 2; m < 8; ++m) {
    const int row = h * 6 + (m - 2);
    const int s = (row >> 1) & 3;
    const size_t base = (size_t)row * 32 + ((g ^ s) << 3) + e;
#pragma unroll
    for (int j = 2; j < 8; ++j) {
      float v = 0.0f;
#pragma unroll
      for (int i = 0; i < 8; ++i) v = fmaf(DBC[m][i], q[i][j], v);
      zc[(size_t)((j - 2) * 16 + kko) * ZSLAB + base] = f2bf(v);
    }
  }
}

// ---------------- 2) fused batched-GEMM + interleave, 768 threads, 3-deep pipeline
// Block (mt 0..63, nt 0..7): out rows [mt*64,+64), cols [nt*512,+512).
// 12 waves; wave wv = (j2 = wv>>1, nhalf = wv&1): M=48 (3 frags), N=32 (2 frags),
// K=512, BK=32. Per-stage buffer = A 18432 B + B 4096 B = 22528 B; 3 buffers.
// STAGING RULE (m104): each gload16 issue must be dest = wave-uniform base + lane*16B.
// Chunk assignment f = q*576 + tid (A) / g = (q*192 + tid-576)&255 (B) satisfies it.
__device__ __forceinline__ void gload16(const unsigned short* g, unsigned short* l) {
  __builtin_amdgcn_global_load_lds(
      (__attribute__((address_space(1))) void*)(g),
      (__attribute__((address_space(3))) void*)(l),
      16, 0, 0);
}

__global__ __launch_bounds__(768, 6) void fused_dct(const unsigned short* __restrict__ zc,
                                                    const unsigned short* __restrict__ dwf,
                                                    float* __restrict__ out) {
  const int bid = blockIdx.x;     // bid = nt*64+mt -> XCD = mt%8: same-mt blocks share L2
  const int mt  = bid & 63;
  const int nt  = bid >> 6;

  // LDS = 3 x 22528 = 67584 B -> 2 blocks/CU. Obuf (38016 B) aliases SM after the loop.
  __shared__ __align__(16) unsigned char SM[67584];
  unsigned short* SMu = (unsigned short*)SM;
  unsigned short* Obuf = (unsigned short*)SM;

  const int tid  = threadIdx.x;
  const int lane = tid & 63;
  const int wv   = tid >> 6;        // 0..11
  const int j2   = wv >> 1;         // 0..5 = j-2
  const int nh   = wv & 1;          // N-half (32 k)
  const int l15  = lane & 15;
  const int hi   = lane >> 4;

  // ---- per-thread staging constants: exactly 2 gload16 per stage per thread.
  // A (tid<576): chunks f0 = tid, f1 = 576+tid of 1152; dest = f*8 elems
  //   -> per issue, wave dest = uniform base + lane*8 elems (16B) as required.
  //   src chunk f: plane j2f = f/192, elem (f/192)*16*ZSLAB + mt*1536 + (f%192)*8.
  // B (tid>=576): chunks g0 = tid-576, g1 = (192+tid-576)&255 of 256; dest 9216+g*8.
  //   g in 0..127 written twice with identical bytes (dup-wrap) -> benign.
  const unsigned short *s0, *s1;
  int d0, d1;                       // LDS elem offsets within a stage buffer
  size_t step;                      // per-kko source stride
  if (tid < 576) {
    const int f0 = tid, f1 = 576 + tid;
    s0 = zc + (size_t)(f0 / 192) * 16 * ZSLAB + mt * 1536 + (f0 % 192) * 8;
    s1 = zc + (size_t)(f1 / 192) * 16 * ZSLAB + mt * 1536 + (f1 % 192) * 8;
    d0 = f0 * 8; d1 = f1 * 8;
    step = ZSLAB;
  } else {
    const int g0 = tid - 576, g1 = (192 + tid - 576) & 255;
    s0 = dwf + nt * 2048 + g0 * 8;
    s1 = dwf + nt * 2048 + g1 * 8;
    d0 = 9216 + g0 * 8; d1 = 9216 + g1 * 8;
    step = DSLAB;
  }

#define STAGE(buf, kko)                                                   \
  do {                                                                    \
    gload16(s0 + (size_t)(kko) * step, SMu + (buf) * 11264 + d0);         \
    gload16(s1 + (size_t)(kko) * step, SMu + (buf) * 11264 + d1);         \
  } while (0)

#define WAITV(n)                                                          \
  do {                                                                    \
    asm volatile("s_waitcnt vmcnt(" #n ")" ::: "memory");                 \
    __builtin_amdgcn_sched_barrier(0);                                    \
  } while (0)

  // read-side offsets (swizzle matches producer: chunk ^= (localrow>>1)&3;
  // mt*48 and nt*64 are multiples of 16 so local-row swizzle == global-row swizzle).
  int aoff[3], boff[2];
#pragma unroll
  for (int mf = 0; mf < 3; ++mf) {
    const int r_ = mf * 16 + l15;
    aoff[mf] = j2 * 1536 + r_ * 32 + ((hi ^ ((r_ >> 1) & 3)) << 3);
  }
#pragma unroll
  for (int nf = 0; nf < 2; ++nf) {
    const int r_ = nh * 32 + nf * 16 + l15;
    boff[nf] = 9216 + r_ * 32 + ((hi ^ ((r_ >> 1) & 3)) << 3);
  }

  f32x4 acc[3][2] = {};

  STAGE(0, 0); STAGE(1, 1); STAGE(2, 2);
#pragma unroll
  for (int t = 0; t < 16; ++t) {
    // at loop head: own outstanding stages = t..min(t+2,15), 2 loads each
    if (t <= 13) { WAITV(4); } else if (t == 14) { WAITV(2); } else { WAITV(0); }
    __builtin_amdgcn_s_barrier();          // stage t visible to all waves
    {
      const unsigned short* Bb = SMu + (t % 3) * 11264;
      bf16x8 bfr[2];
#pragma unroll
      for (int nf = 0; nf < 2; ++nf)
        bfr[nf] = *reinterpret_cast<const bf16x8*>(Bb + boff[nf]);
#pragma unroll
      for (int mf = 0; mf < 3; ++mf) {
        const bf16x8 afr = *reinterpret_cast<const bf16x8*>(Bb + aoff[mf]);
        acc[mf][0] = __builtin_amdgcn_mfma_f32_16x16x32_bf16(afr, bfr[0], acc[mf][0], 0, 0, 0);
        acc[mf][1] = __builtin_amdgcn_mfma_f32_16x16x32_bf16(afr, bfr[1], acc[mf][1], 0, 0, 0);
      }
    }
    asm volatile("s_waitcnt lgkmcnt(0)" ::: "memory");  // own reads of buf t%3 done
    __builtin_amdgcn_s_barrier();                       // everyone's reads done
    if (t <= 12) STAGE(t % 3, t + 3);                   // overwrite with stage t+3
  }
#undef STAGE
#undef WAITV

  __syncthreads();                // close the loop epoch; Obuf may alias all buffers

  // ---- C -> Obuf (plane j2), 48 rows x 64 k, pitch 66
  {
    unsigned short* Ob = Obuf + j2 * 3168;
#pragma unroll
    for (int mf = 0; mf < 3; ++mf)
#pragma unroll
      for (int nf = 0; nf < 2; ++nf)
#pragma unroll
        for (int p = 0; p < 4; ++p)
          Ob[(mf * 16 + hi * 4 + p) * 66 + nh * 32 + nf * 16 + l15] = f2bf(acc[mf][nf][p]);
  }
  __syncthreads();

  // ---- epilogue: 64 rows x 512 f32 cols, coalesced f32x4 incl. mask zeros
  float* outb = out + (size_t)(mt * 64) * 4096 + nt * 512;
  for (int v = tid; v < 8192; v += 768) {
    const int row64 = v >> 7;
    const int c4 = (v & 127) << 2;
    f32x4 val = {0.0f, 0.0f, 0.0f, 0.0f};
    const int m = row64 & 7;
    if (m >= 2) {
      const int row48 = (row64 >> 3) * 6 + (m - 2);
      const int kk = c4 >> 3, jb = c4 & 4;
#pragma unroll
      for (int e = 0; e < 4; ++e) {
        const int j = jb + e;
        if (j >= 2)
          val[e] = bf2f(Obuf[(j - 2) * 3168 + row48 * 66 + kk]);
      }
    }
    *reinterpret_cast<f32x4*>(outb + (size_t)row64 * 4096 + c4) = val;
  }
}

extern "C" void kernel_launch(void* const* d_in, const int* in_sizes, int n_in,
                              void* d_out, int out_size, void* d_ws, size_t ws_size,
                              hipStream_t stream) {
  const float* x = (const float*)d_in[0];
  float* out = (float*)d_out;
  char* ws = (char*)d_ws;

  unsigned short* dwf = (unsigned short*)ws;             // 512 KB
  unsigned short* zc  = (unsigned short*)(ws + 524288);  // 18.87 MB

  pack_all<<<dim3(512, 2), 256, 0, stream>>>(x, zc, dwf);
  fused_dct<<<512, 768, 0, stream>>>(zc, dwf, out);
}

// Round 11
// 42.241 us; speedup vs baseline: 1.2418x; 1.0262x over previous
//
#include <hip/hip_runtime.h>
#include <math.h>

// zc layout: [(j2*16 + kko)][3072 rows][32 w] bf16, chunk-swizzled: logical 8-elem
//   chunk g of row r stored at chunk (g ^ ((r>>1)&3)). Plane = 98304 elems.
// dw layout: [kko(16)][512 k][32 w] bf16, same swizzle keyed on k.
#define ZSLAB 98304
#define DSLAB 16384

typedef __attribute__((ext_vector_type(8))) __bf16 bf16x8;
typedef __attribute__((ext_vector_type(4))) float  f32x4;

__device__ __forceinline__ unsigned short f2bf(float f) {
  union { float f; unsigned u; } v; v.f = f;
  unsigned r = v.u + 0x7fffu + ((v.u >> 16) & 1u);   // RNE
  return (unsigned short)(r >> 16);
}
__device__ __forceinline__ float bf2f_lo(unsigned u) {
  union { unsigned u; float f; } v; v.u = u << 16; return v.f;
}
__device__ __forceinline__ float bf2f_hi(unsigned u) {
  union { unsigned u; float f; } v; v.u = u & 0xffff0000u; return v.f;
}

__device__ const float DBC[8][8] = {
  { 0.35355339f,  0.35355339f,  0.35355339f,  0.35355339f,  0.35355339f,  0.35355339f,  0.35355339f,  0.35355339f},
  { 0.49039264f,  0.41573481f,  0.27778512f,  0.09754516f, -0.09754516f, -0.27778512f, -0.41573481f, -0.49039264f},
  { 0.46193977f,  0.19134172f, -0.19134172f, -0.46193977f, -0.46193977f, -0.19134172f,  0.19134172f,  0.46193977f},
  { 0.41573481f, -0.09754516f, -0.49039264f, -0.27778512f,  0.27778512f,  0.49039264f,  0.09754516f, -0.41573481f},
  { 0.35355339f, -0.35355339f, -0.35355339f,  0.35355339f,  0.35355339f, -0.35355339f, -0.35355339f,  0.35355339f},
  { 0.27778512f, -0.49039264f,  0.09754516f,  0.41573481f, -0.41573481f, -0.09754516f,  0.49039264f, -0.27778512f},
  { 0.19134172f, -0.46193977f,  0.46193977f, -0.19134172f, -0.19134172f,  0.46193977f, -0.46193977f,  0.19134172f},
  { 0.09754516f, -0.27778512f,  0.41573481f, -0.49039264f,  0.49039264f, -0.41573481f,  0.27778512f, -0.09754516f}
};

// ---------------- 1) pack + dw build fused. grid (512, 2) x 256 threads. (unchanged)
__global__ __launch_bounds__(256) void pack_all(const float* __restrict__ x,
                                                unsigned short* __restrict__ zc,
                                                unsigned short* __restrict__ dwf) {
  const int h = blockIdx.x, t = threadIdx.x;

  {
    const int idx = (blockIdx.y * 512 + blockIdx.x) * 256 + t;
    const int k = idx >> 9, w = idx & 511;
    const int n = (k * (2 * w + 1)) & 2047;                     // exact angle reduction
    const float c = __cosf((float)n * 0.0030679615757712823f);  // pi/1024
    const float scale = (k == 0) ? 0.04419417382415922f : 0.0625f;
    const int kko = w >> 5, g = (w >> 3) & 3, e = w & 7, s = (k >> 1) & 3;
    dwf[(size_t)kko * DSLAB + k * 32 + ((g ^ s) << 3) + e] = f2bf(c * scale);
  }

  const int c0 = blockIdx.y * 2048 + t * 8;   // this thread's 8 cols = one w, all j
  const float* xb = x + (size_t)(h * 8) * 4096 + c0;
  float q[8][8];
#pragma unroll
  for (int i = 0; i < 8; ++i) {
    float4 a = *reinterpret_cast<const float4*>(xb + (size_t)i * 4096);
    float4 b = *reinterpret_cast<const float4*>(xb + (size_t)i * 4096 + 4);
    q[i][0] = floorf(a.x * 255.0f); q[i][1] = floorf(a.y * 255.0f);
    q[i][2] = floorf(a.z * 255.0f); q[i][3] = floorf(a.w * 255.0f);
    q[i][4] = floorf(b.x * 255.0f); q[i][5] = floorf(b.y * 255.0f);
    q[i][6] = floorf(b.z * 255.0f); q[i][7] = floorf(b.w * 255.0f);
  }
  const int w0 = c0 >> 3;
  const int kko = w0 >> 5, g = (w0 >> 3) & 3, e = w0 & 7;
#pragma unroll
  for (int m = 2; m < 8; ++m) {
    const int row = h * 6 + (m - 2);
    const int s = (row >> 1) & 3;
    const size_t base = (size_t)row * 32 + ((g ^ s) << 3) + e;
#pragma unroll
    for (int j = 2; j < 8; ++j) {
      float v = 0.0f;
#pragma unroll
      for (int i = 0; i < 8; ++i) v = fmaf(DBC[m][i], q[i][j], v);
      zc[(size_t)((j - 2) * 16 + kko) * ZSLAB + base] = f2bf(v);
    }
  }
}

// ---------------- 2) fused batched-GEMM + interleave, 768 threads, 3-deep pipeline
// Block (mt 0..63, nt 0..7): out rows [mt*64,+64), cols [nt*512,+512).
// 12 waves; wave wv = (j2 = wv>>1, nhalf = wv&1): M=48 (3 frags), N=32 (2 frags),
// K=512, BK=32. Per-stage buffer = A 18432 B + B 4096 B = 22528 B; 3 buffers.
// STAGING RULE (m104): each gload16 issue must be dest = wave-uniform base + lane*16B.
#define OB_PITCH 392   // [row48][k*6 + j2]: write lanes stride 3 words (conflict-free);
                       // 4-row (hi) stride = 784 words = 16 mod 32 -> 2-way = free.
__device__ __forceinline__ void gload16(const unsigned short* g, unsigned short* l) {
  __builtin_amdgcn_global_load_lds(
      (__attribute__((address_space(1))) void*)(g),
      (__attribute__((address_space(3))) void*)(l),
      16, 0, 0);
}

__global__ __launch_bounds__(768, 6) void fused_dct(const unsigned short* __restrict__ zc,
                                                    const unsigned short* __restrict__ dwf,
                                                    float* __restrict__ out) {
  const int bid = blockIdx.x;     // bid = nt*64+mt -> XCD = mt%8: same-mt blocks share L2
  const int mt  = bid & 63;
  const int nt  = bid >> 6;

  // LDS = 3 x 22528 = 67584 B -> 2 blocks/CU. Obuf (48*392*2 = 37632 B) aliases SM.
  __shared__ __align__(16) unsigned char SM[67584];
  unsigned short* SMu = (unsigned short*)SM;
  unsigned short* Obuf = (unsigned short*)SM;

  const int tid  = threadIdx.x;
  const int lane = tid & 63;
  const int wv   = tid >> 6;        // 0..11
  const int j2   = wv >> 1;         // 0..5 = j-2
  const int nh   = wv & 1;          // N-half (32 k)
  const int l15  = lane & 15;
  const int hi   = lane >> 4;

  // per-thread staging: exactly 2 gload16/stage; chunks f0=tid, f1=576+tid (A) keep
  // each issue lane-contiguous (dest = uniform base + lane*16B).
  const unsigned short *s0, *s1;
  int d0, d1;
  size_t step;
  if (tid < 576) {
    const int f0 = tid, f1 = 576 + tid;
    s0 = zc + (size_t)(f0 / 192) * 16 * ZSLAB + mt * 1536 + (f0 % 192) * 8;
    s1 = zc + (size_t)(f1 / 192) * 16 * ZSLAB + mt * 1536 + (f1 % 192) * 8;
    d0 = f0 * 8; d1 = f1 * 8;
    step = ZSLAB;
  } else {
    const int g0 = tid - 576, g1 = (192 + tid - 576) & 255;
    s0 = dwf + nt * 2048 + g0 * 8;
    s1 = dwf + nt * 2048 + g1 * 8;
    d0 = 9216 + g0 * 8; d1 = 9216 + g1 * 8;
    step = DSLAB;
  }

#define STAGE(buf, kko)                                                   \
  do {                                                                    \
    gload16(s0 + (size_t)(kko) * step, SMu + (buf) * 11264 + d0);         \
    gload16(s1 + (size_t)(kko) * step, SMu + (buf) * 11264 + d1);         \
  } while (0)

#define WAITV(n)                                                          \
  do {                                                                    \
    asm volatile("s_waitcnt vmcnt(" #n ")" ::: "memory");                 \
    __builtin_amdgcn_sched_barrier(0);                                    \
  } while (0)

  int aoff[3], boff[2];
#pragma unroll
  for (int mf = 0; mf < 3; ++mf) {
    const int r_ = mf * 16 + l15;
    aoff[mf] = j2 * 1536 + r_ * 32 + ((hi ^ ((r_ >> 1) & 3)) << 3);
  }
#pragma unroll
  for (int nf = 0; nf < 2; ++nf) {
    const int r_ = nh * 32 + nf * 16 + l15;
    boff[nf] = 9216 + r_ * 32 + ((hi ^ ((r_ >> 1) & 3)) << 3);
  }

  f32x4 acc[3][2] = {};

  STAGE(0, 0); STAGE(1, 1); STAGE(2, 2);
#pragma unroll
  for (int t = 0; t < 16; ++t) {
    if (t <= 13) { WAITV(4); } else if (t == 14) { WAITV(2); } else { WAITV(0); }
    __builtin_amdgcn_s_barrier();          // stage t visible to all waves
    {
      const unsigned short* Bb = SMu + (t % 3) * 11264;
      bf16x8 bfr[2], afr[3];
#pragma unroll
      for (int nf = 0; nf < 2; ++nf)
        bfr[nf] = *reinterpret_cast<const bf16x8*>(Bb + boff[nf]);
#pragma unroll
      for (int mf = 0; mf < 3; ++mf)
        afr[mf] = *reinterpret_cast<const bf16x8*>(Bb + aoff[mf]);
      __builtin_amdgcn_s_setprio(1);       // T5: pure-MFMA cluster
#pragma unroll
      for (int mf = 0; mf < 3; ++mf) {
        acc[mf][0] = __builtin_amdgcn_mfma_f32_16x16x32_bf16(afr[mf], bfr[0], acc[mf][0], 0, 0, 0);
        acc[mf][1] = __builtin_amdgcn_mfma_f32_16x16x32_bf16(afr[mf], bfr[1], acc[mf][1], 0, 0, 0);
      }
      __builtin_amdgcn_s_setprio(0);
    }
    asm volatile("s_waitcnt lgkmcnt(0)" ::: "memory");  // own reads of buf t%3 done
    __builtin_amdgcn_s_barrier();                       // everyone's reads done
    if (t <= 12) STAGE(t % 3, t + 3);                   // overwrite with stage t+3
  }
#undef STAGE
#undef WAITV

  __syncthreads();                // close loop epoch; Obuf may alias all buffers

  // ---- C -> Obuf: [row48][k*6 + j2], pitch 392
#pragma unroll
  for (int mf = 0; mf < 3; ++mf)
#pragma unroll
    for (int nf = 0; nf < 2; ++nf)
#pragma unroll
      for (int p = 0; p < 4; ++p)
        Obuf[(mf * 16 + hi * 4 + p) * OB_PITCH + (nh * 32 + nf * 16 + l15) * 6 + j2] =
            f2bf(acc[mf][nf][p]);
  __syncthreads();

  // ---- epilogue: 64 rows x 512 f32 cols; per f32x4 exactly two uniform b32 LDS reads
  float* outb = out + (size_t)(mt * 64) * 4096 + nt * 512;
  for (int v = tid; v < 8192; v += 768) {
    const int row64 = v >> 7;
    const int c4 = (v & 127) << 2;
    f32x4 val = {0.0f, 0.0f, 0.0f, 0.0f};
    const int m = row64 & 7;
    if (m >= 2) {
      const int row48 = (row64 >> 3) * 6 + (m - 2);
      const int kk = c4 >> 3, jb = c4 & 4;               // jb=0 -> j 0..3; jb=4 -> j 4..7
      const unsigned short* Ob = Obuf + row48 * OB_PITCH + kk * 6;
      const unsigned ua = *(const unsigned*)(Ob + (jb >> 1));  // jb=0: j2{0,1}; jb=4: j2{2,3}
      const unsigned ub = *(const unsigned*)(Ob + 4);          //               j2{4,5}
      if (jb) {
        val[0] = bf2f_lo(ua); val[1] = bf2f_hi(ua);
        val[2] = bf2f_lo(ub); val[3] = bf2f_hi(ub);
      } else {
        val[2] = bf2f_lo(ua); val[3] = bf2f_hi(ua);
      }
    }
    *reinterpret_cast<f32x4*>(outb + (size_t)row64 * 4096 + c4) = val;
  }
}

extern "C" void kernel_launch(void* const* d_in, const int* in_sizes, int n_in,
                              void* d_out, int out_size, void* d_ws, size_t ws_size,
                              hipStream_t stream) {
  const float* x = (const float*)d_in[0];
  float* out = (float*)d_out;
  char* ws = (char*)d_ws;

  unsigned short* dwf = (unsigned short*)ws;             // 512 KB
  unsigned short* zc  = (unsigned short*)(ws + 524288);  // 18.87 MB

  pack_all<<<dim3(512, 2), 256, 0, stream>>>(x, zc, dwf);
  fused_dct<<<512, 768, 0, stream>>>(zc, dwf, out);
}